// Round 19
// baseline (50.556 us; speedup 1.0000x reference)
//
#include <hip/hip_runtime.h>
#include <hip/hip_bf16.h>
#include <math.h>

#define NNODES 8192
#define DIM 128
#define SMAX 128
#define HSIZE 16384   // hash table capacity (power of 2)
#define LDA2 68       // LDS stride for [128][64] tiles (16B-aligned, spread banks)
#define NBT 128       // k_tail blocks

// Per-thread index-dtype detection: reads first 4 int64-interpretations of row.
__device__ __forceinline__ int detect64(const void* rowp) {
    const long long* p = (const long long*)rowp;
    int is64 = 1;
#pragma unroll
    for (int i = 0; i < 4; i++) {
        long long v = p[i];
        if (v < 0 || v >= NNODES) is64 = 0;
    }
    return is64;
}

__device__ __forceinline__ int edge_idx(const void* p, int e, int idx64) {
    if (idx64) return (int)((const long long*)p)[e];
    return ((const int*)p)[e];
}

__device__ __forceinline__ int hash_insert(unsigned int* hashK, unsigned int key1) {
    unsigned int h = (key1 * 2654435761u) & (HSIZE - 1);
    for (;;) {
        unsigned int prev = atomicCAS(&hashK[h], 0u, key1);
        if (prev == 0u || prev == key1) return (int)h;
        h = (h + 1) & (HSIZE - 1);
    }
}

// LESSONS LEDGER (measured):
//  r6:  ACQ_REL single-counter + acquire-spin barrier @512 = 44us/barrier.
//  r8:  wave-uniform broadcast ds_reads in GEMM = LDS-pipe bound (40us).
//  r9:  readlane W-broadcast = 2x VALU ops/MAC.
//  r10: readfirstlane->s_load W = SMEM pipe + lgkmcnt(0) serialization (41us).
//  r12: per-block serial scan of 16K hash entries @1% occupancy = 48us.
//  r13: single-counter list append (~3K RMWs) = ~36us.
//  r16: "last block does the GEMM" tail = 512K MACs on ONE CU = ~35us.
//  r18: FENCE-FREE JOIN works (+2.4us): device-scope relaxed atomics at the
//       coherence point; order own ops via syncthreads' vmcnt drain; <=256
//       relaxed RMWs/line ~1us; acquire fence ONLY where plain reads follow.
//  This round: k_hagg+k_final merged via that join (5 -> 4 launches).

// --- K0: zero small scratch (flags/slotmap/cnt0/f0s/r0s ~66KB) ---
__global__ __launch_bounds__(256) void k_zero(float4* z, int n4) {
    int i = blockIdx.x * blockDim.x + threadIdx.x;
    if (i < n4) z[i] = make_float4(0.f, 0.f, 0.f, 0.f);
}

// --- K1: U/V GEMM + cself + nodeid mark/slots + zero hash/xagg ---
__global__ __launch_bounds__(256) void k_dense(
        const float* embed, const float* W1e, const float* b1e,
        const int* nodep, const void* rowp, const void* colp, const float* adjd,
        float* U, float* V, float* cself,
        int* flags, float* cnt0, int* nbr, int* slotmap,
        float* hzero, int nhz, int E) {
    int bid = blockIdx.x;
    int t = threadIdx.x;
    int gid = bid * 256 + t;
    int nodeid = nodep[0];
    int tile = bid >> 1;          // embed rows [tile*64, tile*64+64)
    int colh = bid & 1;           // 0 -> U, 1 -> V

    __shared__ float At[128 * LDA2];   // 34.8 KB: A^T [d][row 0..63]
    __shared__ float Wl[128 * LDA2];   // 34.8 KB: W  [d][col 0..63]
    __shared__ float semb[DIM];

    // zero hash tables + xagg (ordered before k_gates by kernel boundary)
    for (int i = gid; i < nhz; i += 256 * 256) hzero[i] = 0.f;

    const float* Asrc = embed + (size_t)tile * 64 * DIM;
    for (int i = t; i < 64 * DIM; i += 256)
        At[(i & 127) * LDA2 + (i >> 7)] = Asrc[i];
    int doff = colh * 128;
    for (int i = t; i < 128 * 64; i += 256)
        Wl[(i >> 6) * LDA2 + (i & 63)] = W1e[(size_t)(doff + (i >> 6)) * 64 + (i & 63)];
    if (bid == 0 && t < DIM) semb[t] = embed[(size_t)nodeid * DIM + t];
    __syncthreads();

    int rg = t & 15;              // rows rg*4..+3
    int cg = t >> 4;              // cols cg*4..+3
    float acc[4][4];
#pragma unroll
    for (int i = 0; i < 4; i++)
#pragma unroll
        for (int j = 0; j < 4; j++) acc[i][j] = 0.f;

#pragma unroll 4
    for (int d = 0; d < DIM; d++) {
        float4 a4 = *(const float4*)&At[d * LDA2 + rg * 4];
        float4 w4 = *(const float4*)&Wl[d * LDA2 + cg * 4];
        const float* ap = &a4.x;
        const float* wp = &w4.x;
#pragma unroll
        for (int i = 0; i < 4; i++)
#pragma unroll
            for (int j = 0; j < 4; j++)
                acc[i][j] = fmaf(ap[i], wp[j], acc[i][j]);
    }

    float* o = colh ? V : U;
    int n0 = tile * 64;
#pragma unroll
    for (int i = 0; i < 4; i++)
        *(float4*)&o[(size_t)(n0 + rg * 4 + i) * 64 + cg * 4] =
            make_float4(acc[i][0], acc[i][1], acc[i][2], acc[i][3]);

    if (bid == 0 && t < 64) {
        float a = b1e[t];
        for (int d = 0; d < DIM; d++)
            a += semb[d] * W1e[(size_t)(2 * DIM + d) * 64 + t];
        cself[t] = a;
    }

    // mark out-neighbors of nodeid; first-touch slot assignment
    // slotmap: 0 = none, >0 = slot+1, -1 = claimed/overflow
    int idx64 = detect64(rowp);
    for (int e = gid; e < E; e += 256 * 256) {
        int r = edge_idx(rowp, e, idx64);
        if (r != nodeid) continue;
        int c = edge_idx(colp, e, idx64);
        if (c == nodeid) continue;
        atomicAdd(&cnt0[c], adjd[e]);
        if (atomicCAS((unsigned int*)&slotmap[c], 0u, 0xFFFFFFFFu) == 0u) {
            int s = atomicAdd(&flags[1], 1);
            if (s < SMAX) {
                nbr[s] = c;
                __hip_atomic_store(&slotmap[c], s + 1, __ATOMIC_RELAXED,
                                   __HIP_MEMORY_SCOPE_AGENT);
            }
        }
    }
}

// --- K2: classify (compacted) + gate MLP over all E edges ---
__global__ __launch_bounds__(1024) void k_gates(
        const float* adjd, const float* noise, const float* tmp,
        const float* W2e, const float* b2e,
        const void* rowp, const void* colp, const int* nodep,
        const float* U, const float* V, const float* cself,
        const int* slotmap,
        unsigned int* hashK, float* hashC, float* hashF, float* hashR,
        float* f0s, float* r0s, int E) {
    __shared__ int lq[1024];
    __shared__ int lqn;
    int t = threadIdx.x;
    if (t == 0) lqn = 0;
    __syncthreads();
    int idx64 = detect64(rowp);
    int nodeid = nodep[0];
    int e = blockIdx.x * 1024 + t;
    if (e < E) {
        int r = edge_idx(rowp, e, idx64);
        int c = edge_idx(colp, e, idx64);
        if (r != c) {
            int spr = slotmap[r];
            int spc = slotmap[c];
            if (spr > 0 || spc > 0) lq[atomicAdd(&lqn, 1)] = e;
        }
    }
    __syncthreads();
    int n = lqn;
    for (int i = t; i < n; i += 1024) {
        int e2 = lq[i];
        int r = edge_idx(rowp, e2, idx64);
        int c = edge_idx(colp, e2, idx64);
        int spr = slotmap[r];
        int spc = slotmap[c];
        float la = b2e[0];
        const float4* u4 = (const float4*)(U + (size_t)r * 64);
        const float4* v4 = (const float4*)(V + (size_t)c * 64);
        const float4* c4 = (const float4*)cself;
        const float4* w4 = (const float4*)W2e;
#pragma unroll
        for (int d = 0; d < 16; d++) {
            float4 uu = u4[d], vv = v4[d], cc = c4[d], ww = w4[d];
            float h0 = uu.x + vv.x + cc.x;
            float h1 = uu.y + vv.y + cc.y;
            float h2 = uu.z + vv.z + cc.z;
            float h3 = uu.w + vv.w + cc.w;
            la += (h0 > 0.f ? h0 : 0.f) * ww.x + (h1 > 0.f ? h1 : 0.f) * ww.y
                + (h2 > 0.f ? h2 : 0.f) * ww.z + (h3 > 0.f ? h3 : 0.f) * ww.w;
        }
        float nz = noise[e2];
        float gi = (logf(nz) - log1pf(-nz) + la) / tmp[0];
        float v = 1.f / (1.f + expf(-gi));
        if (spr > 0) {
            int sr = spr - 1;
            unsigned int key1 = ((unsigned int)(sr << 13) | (unsigned int)c) + 1u;
            int idx = hash_insert(hashK, key1);
            atomicAdd(&hashC[idx], adjd[e2]);
            atomicAdd(&hashF[idx], v);
            if (c == nodeid) atomicAdd(&r0s[sr], v);
        }
        if (spc > 0) {
            int sc = spc - 1;
            unsigned int key1 = ((unsigned int)(sc << 13) | (unsigned int)r) + 1u;
            int idx = hash_insert(hashK, key1);
            atomicAdd(&hashR[idx], v);
            if (r == nodeid) atomicAdd(&f0s[sc], v);
        }
    }
}

// --- K3: fused hash-aggregate + per-slot GEMM + softmax (fence-free joins) ---
// Phase A: 1024 groups x 16 entries -> xagg (atomicAdds, coherence point).
// Join1: syncthreads (drains vmcnt) -> relaxed arrival -> relaxed spin ->
//        ONE acquire fence/block (phase C reads xagg with PLAIN loads).
// Phase C: block b<ns: h1=relu(xagg@Wg0); glogits += A0*(h1@Wg1) (atomics).
// Join2: relaxed done-counter (r18-validated); last block softmax.
__global__ __launch_bounds__(1024) void k_tail(
        const int* flags, const unsigned int* hashK, const float* hashC,
        const float* hashF, const float* hashR, const float* x,
        const float* cnt0, const int* nbr, const float* f0s, const float* r0s,
        const float* Wg0, const float* Wg1,
        float* xagg, float* glogits, int* arr, int* done, float* out) {
    int bid = blockIdx.x, t = threadIdx.x;
    int gid = bid * 1024 + t;
    int group = gid >> 7;               // 1024 groups of 128 threads
    int tg = t & 127;
    for (int entry = group; entry < HSIZE; entry += NBT * 8) {
        unsigned int key1 = hashK[entry];
        if (key1 == 0u) continue;
        float wgt = hashC[entry] * (hashF[entry] + hashR[entry]) * 0.5f;
        if (wgt == 0.f) continue;
        unsigned int key = key1 - 1u;
        int s = (int)(key >> 13);
        int k = (int)(key & 8191u);
        atomicAdd(&xagg[(size_t)s * DIM + tg], wgt * x[(size_t)k * DIM + tg]);
    }
    __syncthreads();                    // drains each wave's vmcnt pre-barrier
    if (t == 0) {
        asm volatile("s_waitcnt vmcnt(0)" ::: "memory");
        __hip_atomic_fetch_add(arr, 1, __ATOMIC_RELAXED,
                               __HIP_MEMORY_SCOPE_AGENT);
        while (__hip_atomic_load(arr, __ATOMIC_RELAXED,
                                 __HIP_MEMORY_SCOPE_AGENT) < NBT)
            __builtin_amdgcn_s_sleep(2);
        __builtin_amdgcn_fence(__ATOMIC_ACQUIRE, "agent");
    }
    __syncthreads();

    int ns = flags[1]; if (ns > SMAX) ns = SMAX;
    if (bid < ns) {                     // block-uniform: inner barriers legal
        __shared__ float xs[DIM];
        __shared__ float pacc[2][7];
        if (t < DIM) xs[t] = xagg[(size_t)bid * DIM + t];
        __syncthreads();
        if (t < DIM) {
            float h = 0.f;
            for (int d = 0; d < DIM; d++) h = fmaf(xs[d], Wg0[d * DIM + t], h);
            h = h > 0.f ? h : 0.f;
            int wave = t >> 6, lane = t & 63;
            float part[7];
            for (int c = 0; c < 7; c++) {
                float p = h * Wg1[t * 7 + c];
                for (int o = 32; o >= 1; o >>= 1) p += __shfl_xor(p, o, 64);
                part[c] = p;
            }
            if (lane == 0)
                for (int c = 0; c < 7; c++) pacc[wave][c] = part[c];
        }
        __syncthreads();
        if (t == 0) {
            float a0 = cnt0[nbr[bid]] * (f0s[bid] + r0s[bid]) * 0.5f;
            for (int c = 0; c < 7; c++)
                atomicAdd(&glogits[c * 16], a0 * (pacc[0][c] + pacc[1][c]));
        }
    }
    if (t != 0) return;
    asm volatile("s_waitcnt vmcnt(0)" ::: "memory");
    int old = __hip_atomic_fetch_add(done, 1, __ATOMIC_RELAXED,
                                     __HIP_MEMORY_SCOPE_AGENT);
    if (old != NBT - 1) return;
    float v[7], m = -1e30f, ssum = 0.f;
    for (int c = 0; c < 7; c++) {
        v[c] = __hip_atomic_load(&glogits[c * 16], __ATOMIC_RELAXED,
                                 __HIP_MEMORY_SCOPE_AGENT);
        if (v[c] > m) m = v[c];
    }
    for (int c = 0; c < 7; c++) { v[c] = expf(v[c] - m); ssum += v[c]; }
    for (int c = 0; c < 7; c++) out[c] = v[c] / ssum;
}

extern "C" void kernel_launch(void* const* d_in, const int* in_sizes, int n_in,
                              void* d_out, int out_size, void* d_ws, size_t ws_size,
                              hipStream_t stream) {
    const float* x     = (const float*)d_in[0];
    const float* embed = (const float*)d_in[1];
    const float* adjd  = (const float*)d_in[2];
    const float* noise = (const float*)d_in[3];
    const float* tmp   = (const float*)d_in[4];
    const float* W1e   = (const float*)d_in[5];
    const float* b1e   = (const float*)d_in[6];
    const float* W2e   = (const float*)d_in[7];
    const float* b2e   = (const float*)d_in[8];
    const float* Wg0   = (const float*)d_in[9];
    const float* Wg1   = (const float*)d_in[10];
    const void*  rowp  = d_in[11];
    const void*  colp  = d_in[12];
    const int*   nodep = (const int*)d_in[13];
    int E = in_sizes[3];   // noise is float32[E]

    char* w = (char*)d_ws;
    size_t off = 0;
    auto alloc = [&](size_t bytes) -> char* {
        char* p = w + off;
        off = (off + bytes + 255) & ~(size_t)255;
        return p;
    };
    float*        cself   = (float*)alloc(64 * 4);
    int*          nbr     = (int*)  alloc(SMAX * 4);
    float*        U       = (float*)alloc((size_t)NNODES * 64 * 4);
    float*        V       = (float*)alloc((size_t)NNODES * 64 * 4);
    char*         zstart  = w + off;
    int*          flags   = (int*)  alloc(256);      // [1]=ns [2]=arr [3]=done
    float*        glogits = (float*)alloc(512);      // 7 x line-padded (idx c*16)
    int*          slotmap = (int*)  alloc((size_t)NNODES * 4);
    float*        cnt0    = (float*)alloc((size_t)NNODES * 4);
    float*        f0s     = (float*)alloc(SMAX * 4);
    float*        r0s     = (float*)alloc(SMAX * 4);
    size_t zbytes  = (size_t)((w + off) - zstart);
    // hash + xagg: contiguous, zeroed inside k_dense
    unsigned int* hashK   = (unsigned int*)alloc((size_t)HSIZE * 4);
    float*        hashC   = (float*)alloc((size_t)HSIZE * 4);
    float*        hashF   = (float*)alloc((size_t)HSIZE * 4);
    float*        hashR   = (float*)alloc((size_t)HSIZE * 4);
    float*        xagg    = (float*)alloc((size_t)SMAX * DIM * 4);
    int nhz = HSIZE * 4 + SMAX * DIM;   // words from hashK to end of xagg
    int n4 = (int)(zbytes / 16);

    k_zero<<<(n4 + 255) / 256, 256, 0, stream>>>((float4*)zstart, n4);
    k_dense<<<256, 256, 0, stream>>>(embed, W1e, b1e, nodep, rowp, colp, adjd,
                                     U, V, cself, flags, cnt0, nbr, slotmap,
                                     (float*)hashK, nhz, E);
    k_gates<<<(E + 1023) / 1024, 1024, 0, stream>>>(adjd, noise, tmp, W2e, b2e,
                                           rowp, colp, nodep, U, V, cself,
                                           slotmap, hashK, hashC, hashF, hashR,
                                           f0s, r0s, E);
    k_tail<<<NBT, 1024, 0, stream>>>(flags, hashK, hashC, hashF, hashR, x,
                                     cnt0, nbr, f0s, r0s, Wg0, Wg1,
                                     xagg, glogits, &flags[2], &flags[3],
                                     (float*)d_out);
}

// Round 20
// 43.439 us; speedup vs baseline: 1.1638x; 1.1638x over previous
//
#include <hip/hip_runtime.h>
#include <hip/hip_bf16.h>
#include <math.h>

#define NNODES 8192
#define DIM 128
#define SMAX 128
#define HSIZE 16384   // hash table capacity (power of 2)
#define LDA2 68       // LDS stride for [128][64] tiles (16B-aligned, spread banks)

// Per-thread index-dtype detection: reads first 4 int64-interpretations of row.
__device__ __forceinline__ int detect64(const void* rowp) {
    const long long* p = (const long long*)rowp;
    int is64 = 1;
#pragma unroll
    for (int i = 0; i < 4; i++) {
        long long v = p[i];
        if (v < 0 || v >= NNODES) is64 = 0;
    }
    return is64;
}

__device__ __forceinline__ int edge_idx(const void* p, int e, int idx64) {
    if (idx64) return (int)((const long long*)p)[e];
    return ((const int*)p)[e];
}

__device__ __forceinline__ int hash_insert(unsigned int* hashK, unsigned int key1) {
    unsigned int h = (key1 * 2654435761u) & (HSIZE - 1);
    for (;;) {
        unsigned int prev = atomicCAS(&hashK[h], 0u, key1);
        if (prev == 0u || prev == key1) return (int)h;
        h = (h + 1) & (HSIZE - 1);
    }
}

// LESSONS LEDGER (measured):
//  r6:  ACQ_REL single-counter + acquire-spin barrier @512 = 44us/barrier.
//  r8:  wave-uniform broadcast ds_reads in GEMM = LDS-pipe bound (40us).
//  r9:  readlane W-broadcast = 2x VALU ops/MAC.
//  r10: readfirstlane->s_load W = SMEM pipe + lgkmcnt(0) serialization (41us).
//  r12: per-block serial scan of 16K hash entries @1% occupancy = 48us.
//  r13: single-counter list append (~3K RMWs) = ~36us.
//  r16: "last block does the GEMM" tail = 512K MACs on ONE CU = ~35us.
//  r18: FENCE-FREE JOIN works (+2.4us): device-scope relaxed atomics at the
//       coherence point; order own ops via syncthreads' vmcnt drain; <=256
//       relaxed RMWs/line ~1us; acquire fence ONLY where plain reads follow.
//  r19: in-kernel grid join to merge hagg+final REGRESSED +6.8us — a kernel
//       boundary is the cheapest grid barrier (~5us); an in-kernel join that
//       reshapes the joined phases (fewer, spinning blocks) costs more.
//  This round: byte-for-byte revert to r18 (measured best, 43.8us).

// --- K0: zero small scratch (flags/slotmap/cnt0/f0s/r0s ~66KB) ---
__global__ __launch_bounds__(256) void k_zero(float4* z, int n4) {
    int i = blockIdx.x * blockDim.x + threadIdx.x;
    if (i < n4) z[i] = make_float4(0.f, 0.f, 0.f, 0.f);
}

// --- K1: U/V GEMM + cself + nodeid mark/slots + zero hash/xagg ---
// 256 blocks x 256 threads: tile = 64 embed rows, colh picks U|V half of W1e.
// A^T [d][row] & W [d][col] in LDS, 4x4 per-thread register tile.
__global__ __launch_bounds__(256) void k_dense(
        const float* embed, const float* W1e, const float* b1e,
        const int* nodep, const void* rowp, const void* colp, const float* adjd,
        float* U, float* V, float* cself,
        int* flags, float* cnt0, int* nbr, int* slotmap,
        float* hzero, int nhz, int E) {
    int bid = blockIdx.x;
    int t = threadIdx.x;
    int gid = bid * 256 + t;
    int nodeid = nodep[0];
    int tile = bid >> 1;          // embed rows [tile*64, tile*64+64)
    int colh = bid & 1;           // 0 -> U, 1 -> V

    __shared__ float At[128 * LDA2];   // 34.8 KB: A^T [d][row 0..63]
    __shared__ float Wl[128 * LDA2];   // 34.8 KB: W  [d][col 0..63]
    __shared__ float semb[DIM];

    // zero hash tables + xagg (ordered before k_gates by kernel boundary)
    for (int i = gid; i < nhz; i += 256 * 256) hzero[i] = 0.f;

    const float* Asrc = embed + (size_t)tile * 64 * DIM;
    for (int i = t; i < 64 * DIM; i += 256)
        At[(i & 127) * LDA2 + (i >> 7)] = Asrc[i];
    int doff = colh * 128;
    for (int i = t; i < 128 * 64; i += 256)
        Wl[(i >> 6) * LDA2 + (i & 63)] = W1e[(size_t)(doff + (i >> 6)) * 64 + (i & 63)];
    if (bid == 0 && t < DIM) semb[t] = embed[(size_t)nodeid * DIM + t];
    __syncthreads();

    int rg = t & 15;              // rows rg*4..+3
    int cg = t >> 4;              // cols cg*4..+3
    float acc[4][4];
#pragma unroll
    for (int i = 0; i < 4; i++)
#pragma unroll
        for (int j = 0; j < 4; j++) acc[i][j] = 0.f;

#pragma unroll 4
    for (int d = 0; d < DIM; d++) {
        float4 a4 = *(const float4*)&At[d * LDA2 + rg * 4];
        float4 w4 = *(const float4*)&Wl[d * LDA2 + cg * 4];
        const float* ap = &a4.x;
        const float* wp = &w4.x;
#pragma unroll
        for (int i = 0; i < 4; i++)
#pragma unroll
            for (int j = 0; j < 4; j++)
                acc[i][j] = fmaf(ap[i], wp[j], acc[i][j]);
    }

    float* o = colh ? V : U;
    int n0 = tile * 64;
#pragma unroll
    for (int i = 0; i < 4; i++)
        *(float4*)&o[(size_t)(n0 + rg * 4 + i) * 64 + cg * 4] =
            make_float4(acc[i][0], acc[i][1], acc[i][2], acc[i][3]);

    if (bid == 0 && t < 64) {
        float a = b1e[t];
        for (int d = 0; d < DIM; d++)
            a += semb[d] * W1e[(size_t)(2 * DIM + d) * 64 + t];
        cself[t] = a;
    }

    // mark out-neighbors of nodeid; first-touch slot assignment
    // slotmap: 0 = none, >0 = slot+1, -1 = claimed/overflow
    int idx64 = detect64(rowp);
    for (int e = gid; e < E; e += 256 * 256) {
        int r = edge_idx(rowp, e, idx64);
        if (r != nodeid) continue;
        int c = edge_idx(colp, e, idx64);
        if (c == nodeid) continue;
        atomicAdd(&cnt0[c], adjd[e]);
        if (atomicCAS((unsigned int*)&slotmap[c], 0u, 0xFFFFFFFFu) == 0u) {
            int s = atomicAdd(&flags[1], 1);
            if (s < SMAX) {
                nbr[s] = c;
                __hip_atomic_store(&slotmap[c], s + 1, __ATOMIC_RELAXED,
                                   __HIP_MEMORY_SCOPE_AGENT);
            }
        }
    }
}

// --- K2: classify (compacted) + gate MLP over all E edges ---
// Phase 1: scan 1024 edges/block, push relevant IDs to LDS queue (on-CU
// atomics: cheap at any fan-in). Phase 2: dense-lane MLP over the queue.
__global__ __launch_bounds__(1024) void k_gates(
        const float* adjd, const float* noise, const float* tmp,
        const float* W2e, const float* b2e,
        const void* rowp, const void* colp, const int* nodep,
        const float* U, const float* V, const float* cself,
        const int* slotmap,
        unsigned int* hashK, float* hashC, float* hashF, float* hashR,
        float* f0s, float* r0s, int E) {
    __shared__ int lq[1024];
    __shared__ int lqn;
    int t = threadIdx.x;
    if (t == 0) lqn = 0;
    __syncthreads();
    int idx64 = detect64(rowp);
    int nodeid = nodep[0];
    int e = blockIdx.x * 1024 + t;
    if (e < E) {
        int r = edge_idx(rowp, e, idx64);
        int c = edge_idx(colp, e, idx64);
        if (r != c) {
            int spr = slotmap[r];
            int spc = slotmap[c];
            if (spr > 0 || spc > 0) lq[atomicAdd(&lqn, 1)] = e;
        }
    }
    __syncthreads();
    int n = lqn;
    for (int i = t; i < n; i += 1024) {
        int e2 = lq[i];
        int r = edge_idx(rowp, e2, idx64);
        int c = edge_idx(colp, e2, idx64);
        int spr = slotmap[r];
        int spc = slotmap[c];
        float la = b2e[0];
        const float4* u4 = (const float4*)(U + (size_t)r * 64);
        const float4* v4 = (const float4*)(V + (size_t)c * 64);
        const float4* c4 = (const float4*)cself;
        const float4* w4 = (const float4*)W2e;
#pragma unroll
        for (int d = 0; d < 16; d++) {
            float4 uu = u4[d], vv = v4[d], cc = c4[d], ww = w4[d];
            float h0 = uu.x + vv.x + cc.x;
            float h1 = uu.y + vv.y + cc.y;
            float h2 = uu.z + vv.z + cc.z;
            float h3 = uu.w + vv.w + cc.w;
            la += (h0 > 0.f ? h0 : 0.f) * ww.x + (h1 > 0.f ? h1 : 0.f) * ww.y
                + (h2 > 0.f ? h2 : 0.f) * ww.z + (h3 > 0.f ? h3 : 0.f) * ww.w;
        }
        float nz = noise[e2];
        float gi = (logf(nz) - log1pf(-nz) + la) / tmp[0];
        float v = 1.f / (1.f + expf(-gi));
        if (spr > 0) {
            int sr = spr - 1;
            unsigned int key1 = ((unsigned int)(sr << 13) | (unsigned int)c) + 1u;
            int idx = hash_insert(hashK, key1);
            atomicAdd(&hashC[idx], adjd[e2]);
            atomicAdd(&hashF[idx], v);
            if (c == nodeid) atomicAdd(&r0s[sr], v);
        }
        if (spc > 0) {
            int sc = spc - 1;
            unsigned int key1 = ((unsigned int)(sc << 13) | (unsigned int)r) + 1u;
            int idx = hash_insert(hashK, key1);
            atomicAdd(&hashR[idx], v);
            if (r == nodeid) atomicAdd(&f0s[sc], v);
        }
    }
}

// --- K3: hash-aggregate raw x rows into xagg (2048 groups x 8 entries) ---
__global__ __launch_bounds__(1024) void k_hagg(
        const unsigned int* hashK, const float* hashC, const float* hashF,
        const float* hashR, const float* x, float* xagg) {
    int gid = blockIdx.x * blockDim.x + threadIdx.x;
    int group = gid >> 7;
    int tg = gid & 127;
    int ngroups = (256 * 1024) >> 7;
    for (int entry = group; entry < HSIZE; entry += ngroups) {
        unsigned int key1 = hashK[entry];
        if (key1 == 0u) continue;
        float wgt = hashC[entry] * (hashF[entry] + hashR[entry]) * 0.5f;
        if (wgt == 0.f) continue;
        unsigned int key = key1 - 1u;
        int s = (int)(key >> 13);
        int k = (int)(key & 8191u);
        atomicAdd(&xagg[(size_t)s * DIM + tg], wgt * x[(size_t)k * DIM + tg]);
    }
}

// --- K4: block-per-slot: h1 = relu(xagg@Wg0), logits += A0*(h1@Wg1).
// FENCE-FREE JOIN: glogits/done are device-scope atomics (coherence point);
// own adds ordered before arrival by s_waitcnt vmcnt(0) (a wait, NOT a wbL2).
// Last-arriving block reads glogits via relaxed atomic loads -> softmax. ---
__global__ __launch_bounds__(128) void k_final(
        const int* flags, const float* xagg, const float* cnt0, const int* nbr,
        const float* f0s, const float* r0s, const float* Wg0, const float* Wg1,
        float* glogits, int* done, float* out) {
    int b = blockIdx.x, t = threadIdx.x;
    int ns = flags[1]; if (ns > SMAX) ns = SMAX;
    if (b < ns) {
        __shared__ float xs[DIM];
        __shared__ float pacc[2][7];
        xs[t] = xagg[(size_t)b * DIM + t];
        __syncthreads();
        float h = 0.f;
        for (int d = 0; d < DIM; d++) h = fmaf(xs[d], Wg0[d * DIM + t], h);
        h = h > 0.f ? h : 0.f;
        int wave = t >> 6, lane = t & 63;
        float part[7];
        for (int c = 0; c < 7; c++) {
            float p = h * Wg1[t * 7 + c];
            for (int o = 32; o >= 1; o >>= 1) p += __shfl_xor(p, o, 64);
            part[c] = p;
        }
        if (lane == 0)
            for (int c = 0; c < 7; c++) pacc[wave][c] = part[c];
        __syncthreads();
        if (t == 0) {
            float a0 = cnt0[nbr[b]] * (f0s[b] + r0s[b]) * 0.5f;
            for (int c = 0; c < 7; c++)
                atomicAdd(&glogits[c * 16], a0 * (pacc[0][c] + pacc[1][c]));
        }
    }
    if (t != 0) return;
    // ensure this block's glogits atomics have REACHED the coherence point
    asm volatile("s_waitcnt vmcnt(0)" ::: "memory");
    int old = __hip_atomic_fetch_add(done, 1, __ATOMIC_RELAXED,
                                     __HIP_MEMORY_SCOPE_AGENT);
    if (old != SMAX - 1) return;
    // last arrival: all blocks' adds complete; read via atomic loads (L2-coherent)
    float v[7], m = -1e30f, ssum = 0.f;
    for (int c = 0; c < 7; c++) {
        v[c] = __hip_atomic_load(&glogits[c * 16], __ATOMIC_RELAXED,
                                 __HIP_MEMORY_SCOPE_AGENT);
        if (v[c] > m) m = v[c];
    }
    for (int c = 0; c < 7; c++) { v[c] = expf(v[c] - m); ssum += v[c]; }
    for (int c = 0; c < 7; c++) out[c] = v[c] / ssum;
}

extern "C" void kernel_launch(void* const* d_in, const int* in_sizes, int n_in,
                              void* d_out, int out_size, void* d_ws, size_t ws_size,
                              hipStream_t stream) {
    const float* x     = (const float*)d_in[0];
    const float* embed = (const float*)d_in[1];
    const float* adjd  = (const float*)d_in[2];
    const float* noise = (const float*)d_in[3];
    const float* tmp   = (const float*)d_in[4];
    const float* W1e   = (const float*)d_in[5];
    const float* b1e   = (const float*)d_in[6];
    const float* W2e   = (const float*)d_in[7];
    const float* b2e   = (const float*)d_in[8];
    const float* Wg0   = (const float*)d_in[9];
    const float* Wg1   = (const float*)d_in[10];
    const void*  rowp  = d_in[11];
    const void*  colp  = d_in[12];
    const int*   nodep = (const int*)d_in[13];
    int E = in_sizes[3];   // noise is float32[E]

    char* w = (char*)d_ws;
    size_t off = 0;
    auto alloc = [&](size_t bytes) -> char* {
        char* p = w + off;
        off = (off + bytes + 255) & ~(size_t)255;
        return p;
    };
    float*        cself   = (float*)alloc(64 * 4);
    int*          nbr     = (int*)  alloc(SMAX * 4);
    float*        U       = (float*)alloc((size_t)NNODES * 64 * 4);
    float*        V       = (float*)alloc((size_t)NNODES * 64 * 4);
    char*         zstart  = w + off;
    int*          flags   = (int*)  alloc(256);      // [1]=ns [2]=done
    float*        glogits = (float*)alloc(512);      // 7 x line-padded (idx c*16)
    int*          slotmap = (int*)  alloc((size_t)NNODES * 4);
    float*        cnt0    = (float*)alloc((size_t)NNODES * 4);
    float*        f0s     = (float*)alloc(SMAX * 4);
    float*        r0s     = (float*)alloc(SMAX * 4);
    size_t zbytes  = (size_t)((w + off) - zstart);
    // hash + xagg: contiguous, zeroed inside k_dense
    unsigned int* hashK   = (unsigned int*)alloc((size_t)HSIZE * 4);
    float*        hashC   = (float*)alloc((size_t)HSIZE * 4);
    float*        hashF   = (float*)alloc((size_t)HSIZE * 4);
    float*        hashR   = (float*)alloc((size_t)HSIZE * 4);
    float*        xagg    = (float*)alloc((size_t)SMAX * DIM * 4);
    int nhz = HSIZE * 4 + SMAX * DIM;   // words from hashK to end of xagg
    int n4 = (int)(zbytes / 16);

    k_zero<<<(n4 + 255) / 256, 256, 0, stream>>>((float4*)zstart, n4);
    k_dense<<<256, 256, 0, stream>>>(embed, W1e, b1e, nodep, rowp, colp, adjd,
                                     U, V, cself, flags, cnt0, nbr, slotmap,
                                     (float*)hashK, nhz, E);
    k_gates<<<(E + 1023) / 1024, 1024, 0, stream>>>(adjd, noise, tmp, W2e, b2e,
                                           rowp, colp, nodep, U, V, cself,
                                           slotmap, hashK, hashC, hashF, hashR,
                                           f0s, r0s, E);
    k_hagg<<<256, 1024, 0, stream>>>(hashK, hashC, hashF, hashR, x, xagg);
    k_final<<<SMAX, 128, 0, stream>>>(flags, xagg, cnt0, nbr, f0s, r0s,
                                      Wg0, Wg1, glogits, &flags[2],
                                      (float*)d_out);
}